// Round 3
// baseline (626.666 us; speedup 1.0000x reference)
//
#include <hip/hip_runtime.h>
#include <hip/hip_bf16.h>
#include <stdint.h>

typedef unsigned short u16;
typedef __bf16 bf16x8 __attribute__((ext_vector_type(8)));
typedef float f32x4 __attribute__((ext_vector_type(4)));

#define INVT 14.2857142857142857f  // 1/0.07

__device__ __forceinline__ u16 f2b(float f) {
  __hip_bfloat16 h = __float2bfloat16(f);
  return __builtin_bit_cast(u16, h);
}
__device__ __forceinline__ float b2f(u16 u) {
  union { uint32_t i; float f; } z; z.i = ((uint32_t)u) << 16; return z.f;
}
__device__ __forceinline__ void g2l16(const void* g, void* l) {
  __builtin_amdgcn_global_load_lds(
      (__attribute__((address_space(1))) void*)(uintptr_t)g,
      (__attribute__((address_space(3))) void*)(uint32_t)(uintptr_t)l, 16, 0, 0);
}

// ---- prep: feat (b,c,hw) -> Xhi/Xlo bf16 (n, c), n = b*1024+hw; + xnorm ------
__global__ __launch_bounds__(256) void prep_x(const float* __restrict__ feat,
    u16* __restrict__ Xhi, u16* __restrict__ Xlo, float* __restrict__ xnorm) {
  __shared__ float sm[64][65];
  int b = blockIdx.x >> 4;
  int hw0 = (blockIdx.x & 15) << 6;
  int t = threadIdx.x;
  int hwi = t & 63, ci0 = t >> 6;
  float xs2[2] = {0.f, 0.f};
  int cj = t & 7;
  for (int c0 = 0; c0 < 512; c0 += 64) {
    for (int ci = ci0; ci < 64; ci += 4)
      sm[ci][hwi] = feat[((b * 512 + c0 + ci) << 10) + hw0 + hwi];
    __syncthreads();
    for (int w = 0; w < 2; ++w) {
      int hj = (t >> 3) + (w << 5);
      int n = (b << 10) + hw0 + hj;
      uint32_t hp[4], lp[4];
      for (int p = 0; p < 4; ++p) {
        float v0 = sm[cj * 8 + p * 2 + 0][hj];
        float v1 = sm[cj * 8 + p * 2 + 1][hj];
        xs2[w] += v0 * v0 + v1 * v1;
        u16 h0 = f2b(v0), h1 = f2b(v1);
        u16 l0 = f2b(v0 - b2f(h0)), l1 = f2b(v1 - b2f(h1));
        hp[p] = (uint32_t)h0 | ((uint32_t)h1 << 16);
        lp[p] = (uint32_t)l0 | ((uint32_t)l1 << 16);
      }
      *(uint4*)(Xhi + n * 512 + c0 + cj * 8) = make_uint4(hp[0], hp[1], hp[2], hp[3]);
      *(uint4*)(Xlo + n * 512 + c0 + cj * 8) = make_uint4(lp[0], lp[1], lp[2], lp[3]);
    }
    __syncthreads();
  }
  // reduce Σx² across the 8 lanes sharing each hj (consecutive lanes in-wave)
  for (int w = 0; w < 2; ++w) {
    float v = xs2[w];
    v += __shfl_xor(v, 1); v += __shfl_xor(v, 2); v += __shfl_xor(v, 4);
    if (cj == 0) {
      int hj = (t >> 3) + (w << 5);
      xnorm[(b << 10) + hw0 + hj] = v;
    }
  }
}

// ---------------- prep: codebook -> Ehi/Elo + enorm (exact fp32) --------------
__global__ __launch_bounds__(64) void prep_e(const float* __restrict__ cb,
    u16* __restrict__ Ehi, u16* __restrict__ Elo, float* __restrict__ enorm) {
  int k = blockIdx.x, l = threadIdx.x;
  float nrm = 0.f;
  for (int it = 0; it < 2; ++it) {
    int c = (l + it * 64) * 4;
    float4 v = *(const float4*)(cb + k * 512 + c);
    nrm += v.x * v.x + v.y * v.y + v.z * v.z + v.w * v.w;
    u16 h0 = f2b(v.x), h1 = f2b(v.y), h2 = f2b(v.z), h3 = f2b(v.w);
    uint2 hp; hp.x = (uint32_t)h0 | ((uint32_t)h1 << 16);
    hp.y = (uint32_t)h2 | ((uint32_t)h3 << 16);
    *(uint2*)(Ehi + k * 512 + c) = hp;
    u16 q0 = f2b(v.x - b2f(h0)), q1 = f2b(v.y - b2f(h1));
    u16 q2 = f2b(v.z - b2f(h2)), q3 = f2b(v.w - b2f(h3));
    uint2 lq; lq.x = (uint32_t)q0 | ((uint32_t)q1 << 16);
    lq.y = (uint32_t)q2 | ((uint32_t)q3 << 16);
    *(uint2*)(Elo + k * 512 + c) = lq;
  }
  for (int o = 32; o; o >>= 1) nrm += __shfl_xor(nrm, o);
  if (l == 0) enorm[k] = nrm;
}

// ---------------- prep: Et[c][k] = bf16(codebook[k][c]) (for q GEMM) ----------
__global__ __launch_bounds__(256) void prep_et(const u16* __restrict__ Ehi, u16* __restrict__ Et) {
  __shared__ u16 sm[64][68];
  int k0 = (blockIdx.x & 63) << 6;
  int c0 = (blockIdx.x >> 6) << 6;
  int t = threadIdx.x;
  for (int idx = t; idx < 1024; idx += 256) {
    int ki = idx >> 4, cc = idx & 15;
    uint2 v = *(const uint2*)(Ehi + (k0 + ki) * 512 + c0 + cc * 4);
    *(uint2*)&sm[ki][cc * 4] = v;
  }
  __syncthreads();
  for (int idx = t; idx < 1024; idx += 256) {
    int ci = idx >> 4, kc = idx & 15;
    u16 a0 = sm[kc * 4 + 0][ci], a1 = sm[kc * 4 + 1][ci];
    u16 a2 = sm[kc * 4 + 2][ci], a3 = sm[kc * 4 + 3][ci];
    uint2 o; o.x = (uint32_t)a0 | ((uint32_t)a1 << 16);
    o.y = (uint32_t)a2 | ((uint32_t)a3 << 16);
    *(uint2*)(Et + (c0 + ci) * 4096 + k0 + kc * 4) = o;
  }
}

// ================= GEMM1: 256x256 tile, BK=64, 8 waves, 8-phase ===============
__device__ __forceinline__ void stageA_g1(const u16* __restrict__ g, u16* l, int h, int t) {
  int r0 = t >> 3, c = ((t & 7) ^ (r0 & 7)) * 8, cw = (t & 7) * 8;
  int ra = h * 64 + r0, rb = 128 + h * 64 + r0;
  g2l16(g + ra * 512 + c, l + ra * 64 + cw);
  g2l16(g + rb * 512 + c, l + rb * 64 + cw);
}
__device__ __forceinline__ void stageB_g1(const u16* __restrict__ g, u16* l, int hb, int t) {
  int r0 = t >> 3, c = ((t & 7) ^ (r0 & 7)) * 8, cw = (t & 7) * 8;
  int ra = (r0 >> 5) * 64 + hb * 32 + (r0 & 31);
  int rb = ((r0 + 64) >> 5) * 64 + hb * 32 + (r0 & 31);
  g2l16(g + ra * 512 + c, l + ra * 64 + cw);
  g2l16(g + rb * 512 + c, l + rb * 64 + cw);
}

template<int Q>
__device__ __forceinline__ void phase_ld(const u16* Ab, const u16* Bb,
    int wm, int wn, int lane16, int kl, bf16x8 (&af)[4][2], bf16x8 (&bf2)[2][2]) {
  int sw = lane16 & 7;
  if constexpr (Q == 0 || Q == 2) {
#pragma unroll
    for (int m = 0; m < 4; ++m)
#pragma unroll
      for (int s = 0; s < 2; ++s)
        af[m][s] = *(const bf16x8*)(Ab + (wm * 128 + ((Q >> 1) * 4 + m) * 16 + lane16) * 64
                                    + (((s * 4 + kl) ^ sw) * 8));
  }
  if constexpr (Q != 2) {
    constexpr int NF0 = (Q == 1) ? 2 : 0;
#pragma unroll
    for (int n = 0; n < 2; ++n)
#pragma unroll
      for (int s = 0; s < 2; ++s)
        bf2[n][s] = *(const bf16x8*)(Bb + (wn * 64 + (NF0 + n) * 16 + lane16) * 64
                                     + (((s * 4 + kl) ^ sw) * 8));
  }
}
template<int Q>
__device__ __forceinline__ void phase_mm(bf16x8 (&af)[4][2], bf16x8 (&bf2)[2][2],
                                         f32x4 (&acc)[8][4]) {
  constexpr int MQ = (Q >> 1) * 4;
  constexpr int NF0 = (Q == 1 || Q == 2) ? 2 : 0;
#pragma unroll
  for (int m = 0; m < 4; ++m)
#pragma unroll
    for (int n = 0; n < 2; ++n)
#pragma unroll
      for (int s = 0; s < 2; ++s)
        acc[MQ + m][NF0 + n] = __builtin_amdgcn_mfma_f32_16x16x32_bf16(
            af[m][s], bf2[n][s], acc[MQ + m][NF0 + n], 0, 0, 0);
}

#define FENCE() asm volatile("" ::: "memory")
#define BAR() __builtin_amdgcn_s_barrier()
#define VMW4() asm volatile("s_waitcnt vmcnt(4)" ::: "memory")
#define VMW0() asm volatile("s_waitcnt vmcnt(0)" ::: "memory")

__global__ __launch_bounds__(512, 2) void gemm1_8ph(const u16* __restrict__ Xhi,
    const u16* __restrict__ Xlo, const u16* __restrict__ Ehi, const u16* __restrict__ Elo,
    const float* __restrict__ xnorm, const float* __restrict__ enorm, float* __restrict__ D) {
  __shared__ __align__(16) u16 lds[2][2][256 * 64];  // 128 KB
  int bid = blockIdx.x;
  int s = (bid & 7) * 128 + (bid >> 3);   // XCD swizzle, 1024 % 8 == 0 -> bijective
  int rt = s >> 4, ct = s & 15;
  int n0 = rt << 8, k0 = ct << 8;
  int t = threadIdx.x;
  int l = t & 63, w = t >> 6;
  int wm = w >> 2, wn = w & 3;
  int lane16 = l & 15, kl = l >> 4;

  u16* lA0 = &lds[0][0][0]; u16* lB0 = &lds[0][1][0];
  u16* lA1 = &lds[1][0][0]; u16* lB1 = &lds[1][1][0];

  auto gA = [&](int kt) { return ((kt >> 3) == 1 ? Xlo : Xhi) + n0 * 512 + (kt & 7) * 64; };
  auto gB = [&](int kt) { return ((kt >> 3) == 2 ? Elo : Ehi) + k0 * 512 + (kt & 7) * 64; };

  f32x4 acc[8][4];
#pragma unroll
  for (int m = 0; m < 8; ++m)
#pragma unroll
    for (int n = 0; n < 4; ++n) acc[m][n] = f32x4{0.f, 0.f, 0.f, 0.f};
  bf16x8 af[4][2], bf2[2][2];

  stageA_g1(gA(0), lA0, 0, t);
  stageB_g1(gB(0), lB0, 1, t);
  stageB_g1(gB(0), lB0, 0, t);
  stageA_g1(gA(0), lA0, 1, t);
  stageA_g1(gA(1), lA1, 0, t);
  stageB_g1(gB(1), lB1, 1, t);
  VMW4();
  BAR();

#pragma unroll 1
  for (int i = 0; i < 12; ++i) {
    int ktO = 2 * i + 1;
    int ktE2 = 2 * i + 2, ktO2 = 2 * i + 3;
    bool more = (i < 11);
    phase_ld<0>(lA0, lB0, wm, wn, lane16, kl, af, bf2);
    stageB_g1(gB(ktO), lB1, 0, t);
    FENCE(); BAR();
    __builtin_amdgcn_s_setprio(1); phase_mm<0>(af, bf2, acc); __builtin_amdgcn_s_setprio(0);
    FENCE(); BAR();
    phase_ld<1>(lA0, lB0, wm, wn, lane16, kl, af, bf2);
    stageA_g1(gA(ktO), lA1, 1, t);
    FENCE(); BAR();
    __builtin_amdgcn_s_setprio(1); phase_mm<1>(af, bf2, acc); __builtin_amdgcn_s_setprio(0);
    FENCE(); BAR();
    phase_ld<2>(lA0, lB0, wm, wn, lane16, kl, af, bf2);
    if (more) stageA_g1(gA(ktE2), lA0, 0, t);
    FENCE(); BAR();
    __builtin_amdgcn_s_setprio(1); phase_mm<2>(af, bf2, acc); __builtin_amdgcn_s_setprio(0);
    FENCE(); BAR();
    phase_ld<3>(lA0, lB0, wm, wn, lane16, kl, af, bf2);
    if (more) stageB_g1(gB(ktE2), lB0, 1, t);
    FENCE(); BAR();
    __builtin_amdgcn_s_setprio(1); phase_mm<3>(af, bf2, acc); __builtin_amdgcn_s_setprio(0);
    if (i == 11) { VMW0(); } else { VMW4(); }
    BAR();
    phase_ld<0>(lA1, lB1, wm, wn, lane16, kl, af, bf2);
    if (more) stageB_g1(gB(ktE2), lB0, 0, t);
    FENCE(); BAR();
    __builtin_amdgcn_s_setprio(1); phase_mm<0>(af, bf2, acc); __builtin_amdgcn_s_setprio(0);
    FENCE(); BAR();
    phase_ld<1>(lA1, lB1, wm, wn, lane16, kl, af, bf2);
    if (more) stageA_g1(gA(ktE2), lA0, 1, t);
    FENCE(); BAR();
    __builtin_amdgcn_s_setprio(1); phase_mm<1>(af, bf2, acc); __builtin_amdgcn_s_setprio(0);
    FENCE(); BAR();
    phase_ld<2>(lA1, lB1, wm, wn, lane16, kl, af, bf2);
    if (more) stageA_g1(gA(ktO2), lA1, 0, t);
    FENCE(); BAR();
    __builtin_amdgcn_s_setprio(1); phase_mm<2>(af, bf2, acc); __builtin_amdgcn_s_setprio(0);
    FENCE(); BAR();
    phase_ld<3>(lA1, lB1, wm, wn, lane16, kl, af, bf2);
    if (more) stageB_g1(gB(ktO2), lB1, 1, t);
    FENCE(); BAR();
    __builtin_amdgcn_s_setprio(1); phase_mm<3>(af, bf2, acc); __builtin_amdgcn_s_setprio(0);
    if (more) { VMW4(); }
    BAR();
  }

  float en[4];
#pragma unroll
  for (int nf = 0; nf < 4; ++nf) en[nf] = enorm[k0 + wn * 64 + nf * 16 + lane16];
#pragma unroll
  for (int mf = 0; mf < 8; ++mf) {
#pragma unroll
    for (int r = 0; r < 4; ++r) {
      int row = n0 + wm * 128 + mf * 16 + kl * 4 + r;
      float xv = xnorm[row];
      float* Drow = D + (size_t)row * 4096 + k0 + wn * 64 + lane16;
#pragma unroll
      for (int nf = 0; nf < 4; ++nf)
        Drow[nf * 16] = xv + en[nf] - 2.0f * acc[mf][nf][r];
    }
  }
}

// ------- fused: online stats (pass 1) + softmax outputs (pass 2) --------------
// Block = 32 rows, 256 threads; 8 lanes per row. Pass 1: streaming online
// two-temperature softmax stats (running min + rescaled sums), shfl-combined
// across the 8 lanes. Pass 2: re-read D (L3-warm), write assignment
// (LDS-transposed) + P bf16.
__global__ __launch_bounds__(256) void softmax_fused(const float* __restrict__ D,
    float* __restrict__ assign, u16* __restrict__ P) {
  __shared__ float tt[128][33];
  int n0 = blockIdx.x << 5;
  int b = n0 >> 10, hw0 = n0 & 1023;
  int t = threadIdx.x;
  int i = t >> 3, jc = t & 7;
  const float* Dr = D + (size_t)(n0 + i) * 4096;

  // ---- pass 1: online stats over this thread's 512 columns ----
  float m = 3.4e38f, s1 = 0.f, sT = 0.f;
#pragma unroll 4
  for (int it = 0; it < 128; ++it) {
    float4 dv = *(const float4*)(Dr + (jc + it * 8) * 4);
    float lm = fminf(fminf(dv.x, dv.y), fminf(dv.z, dv.w));
    if (lm < m) {
      float d1 = lm - m;                 // <= 0
      s1 *= __expf(d1);
      sT *= __expf(d1 * INVT);
      m = lm;
    }
    s1 += __expf(m - dv.x) + __expf(m - dv.y) + __expf(m - dv.z) + __expf(m - dv.w);
    sT += __expf((m - dv.x) * INVT) + __expf((m - dv.y) * INVT)
        + __expf((m - dv.z) * INVT) + __expf((m - dv.w) * INVT);
  }
  // combine across the 8 lanes of this row (butterfly keeps all lanes updated)
#pragma unroll
  for (int o = 1; o < 8; o <<= 1) {
    float mo = __shfl_xor(m, o);
    float s1o = __shfl_xor(s1, o);
    float sTo = __shfl_xor(sT, o);
    float mc = fminf(m, mo);
    s1 = s1 * __expf(mc - m) + s1o * __expf(mc - mo);
    sT = sT * __expf((mc - m) * INVT) + sTo * __expf((mc - mo) * INVT);
    m = mc;
  }
  float is1 = 1.0f / s1, isT = 1.0f / sT;

  // ---- pass 2: outputs ----
  float* assignB = assign + b * 4194304 + hw0;
  u16* Pr = P + (size_t)(n0 + i) * 4096;
  for (int kt = 0; kt < 32; ++kt) {
    int kb = kt << 7;
    for (int it = 0; it < 4; ++it) {
      int col4 = (jc + it * 8) * 4;
      float4 dv = *(const float4*)(Dr + kb + col4);
      float e0 = m - dv.x, e1 = m - dv.y, e2 = m - dv.z, e3 = m - dv.w;
      u16 p0 = f2b(__expf(e0) * is1), p1 = f2b(__expf(e1) * is1);
      u16 p2 = f2b(__expf(e2) * is1), p3 = f2b(__expf(e3) * is1);
      uint2 pp; pp.x = (uint32_t)p0 | ((uint32_t)p1 << 16);
      pp.y = (uint32_t)p2 | ((uint32_t)p3 << 16);
      *(uint2*)(Pr + kb + col4) = pp;
      tt[col4 + 0][i] = __expf(e0 * INVT) * isT;
      tt[col4 + 1][i] = __expf(e1 * INVT) * isT;
      tt[col4 + 2][i] = __expf(e2 * INVT) * isT;
      tt[col4 + 3][i] = __expf(e3 * INVT) * isT;
    }
    __syncthreads();
    for (int idx = t; idx < 1024; idx += 256) {
      int j = idx >> 3, ic = idx & 7;
      float4 o;
      o.x = tt[j][ic * 4 + 0]; o.y = tt[j][ic * 4 + 1];
      o.z = tt[j][ic * 4 + 2]; o.w = tt[j][ic * 4 + 3];
      *(float4*)(assignB + (kb + j) * 1024 + ic * 4) = o;
    }
    __syncthreads();
  }
}

// ---------------- GEMM2: q^T = Et (c x K) . P^T  -> (b, c, hw) directly -------
__global__ __launch_bounds__(256) void gemm2(const u16* __restrict__ Et,
    const u16* __restrict__ P, float* __restrict__ Q) {
  __shared__ u16 As[2][128 * 32];
  __shared__ u16 Bs[2][128 * 32];
  int bid = blockIdx.x;
  int s = (bid & 7) * 64 + (bid >> 3);
  int rt = s >> 7, ct = s & 127;
  int c0 = rt << 7, n0 = ct << 7;
  int t = threadIdx.x;
  auto stage = [&](int buf, int cc) {
    int cin = cc << 5;
    for (int i = 0; i < 2; ++i) {
      int idx = i * 256 + t;
      int row = idx >> 2, chv = idx & 3;
      g2l16(Et + (c0 + row) * 4096 + cin + chv * 8, &As[buf][idx * 8]);
      g2l16(P + (n0 + row) * 4096 + cin + chv * 8, &Bs[buf][idx * 8]);
    }
  };
  int l = t & 63, w = t >> 6;
  int wr = (w >> 1) << 6, wc = (w & 1) << 6;
  int lane16 = l & 15, kl = l >> 4;
  f32x4 acc[4][4];
  for (int m = 0; m < 4; ++m)
    for (int nn = 0; nn < 4; ++nn) acc[m][nn] = f32x4{0.f, 0.f, 0.f, 0.f};
  stage(0, 0);
  __syncthreads();
  for (int cc = 0; cc < 128; ++cc) {
    int buf = cc & 1;
    if (cc + 1 < 128) stage(buf ^ 1, cc + 1);
    bf16x8 af[4], bfr[4];
    for (int m = 0; m < 4; ++m)
      af[m] = *(const bf16x8*)&As[buf][(wr + m * 16 + lane16) * 32 + kl * 8];
    for (int nn = 0; nn < 4; ++nn)
      bfr[nn] = *(const bf16x8*)&Bs[buf][(wc + nn * 16 + lane16) * 32 + kl * 8];
    for (int m = 0; m < 4; ++m)
      for (int nn = 0; nn < 4; ++nn)
        acc[m][nn] = __builtin_amdgcn_mfma_f32_16x16x32_bf16(af[m], bfr[nn], acc[m][nn], 0, 0, 0);
    __syncthreads();
  }
  for (int m = 0; m < 4; ++m) {
    for (int r = 0; r < 4; ++r) {
      int crow = c0 + wr + m * 16 + kl * 4 + r;
      for (int nn = 0; nn < 4; ++nn) {
        int col = n0 + wc + nn * 16 + lane16;
        int bb = col >> 10, hw = col & 1023;
        Q[bb * 524288 + crow * 1024 + hw] = acc[m][nn][r];
      }
    }
  }
}

extern "C" void kernel_launch(void* const* d_in, const int* in_sizes, int n_in,
                              void* d_out, int out_size, void* d_ws, size_t ws_size,
                              hipStream_t stream) {
  const float* feat = (const float*)d_in[0];   // (16, 512, 32, 32)
  const float* cb = (const float*)d_in[1];     // (4096, 512)
  float* out = (float*)d_out;
  float* q_out = out;                          // 8388608
  float* a_out = out + 8388608;                // 67108864
  float* d_dist = out + 75497472;              // 67108864

  char* ws = (char*)d_ws;
  u16* Xhi = (u16*)(ws + 0);
  u16* Xlo = (u16*)(ws + 16777216);
  u16* Ehi = (u16*)(ws + 33554432);
  u16* Elo = (u16*)(ws + 37748736);
  u16* Et  = (u16*)(ws + 41943040);
  float* xnorm = (float*)(ws + 46137344);
  float* enorm = (float*)(ws + 46202880);
  u16* P = (u16*)(ws + 46481408);              // ends at ~180.7 MB

  prep_x<<<256, 256, 0, stream>>>(feat, Xhi, Xlo, xnorm);
  prep_e<<<4096, 64, 0, stream>>>(cb, Ehi, Elo, enorm);
  prep_et<<<512, 256, 0, stream>>>(Ehi, Et);
  gemm1_8ph<<<1024, 512, 0, stream>>>(Xhi, Xlo, Ehi, Elo, xnorm, enorm, d_dist);
  softmax_fused<<<512, 256, 0, stream>>>(d_dist, a_out, P);
  gemm2<<<512, 256, 0, stream>>>(Et, P, q_out);
}

// Round 4
// 531.727 us; speedup vs baseline: 1.1785x; 1.1785x over previous
//
#include <hip/hip_runtime.h>
#include <hip/hip_bf16.h>
#include <stdint.h>

typedef unsigned short u16;
typedef __bf16 bf16x8 __attribute__((ext_vector_type(8)));
typedef float f32x4 __attribute__((ext_vector_type(4)));

#define INVT 14.2857142857142857f  // 1/0.07
#define CSH  32.0f                 // extra shift on T-path exponents (softmax-invariant)

__device__ __forceinline__ u16 f2b(float f) {
  __hip_bfloat16 h = __float2bfloat16(f);
  return __builtin_bit_cast(u16, h);
}
__device__ __forceinline__ float b2f(u16 u) {
  union { uint32_t i; float f; } z; z.i = ((uint32_t)u) << 16; return z.f;
}
__device__ __forceinline__ void g2l16(const void* g, void* l) {
  __builtin_amdgcn_global_load_lds(
      (__attribute__((address_space(1))) void*)(uintptr_t)g,
      (__attribute__((address_space(3))) void*)(uint32_t)(uintptr_t)l, 16, 0, 0);
}

// ---- prep: feat (b,c,hw) -> Xhi/Xlo bf16 (n, c), n = b*1024+hw; + xnorm ------
__global__ __launch_bounds__(256) void prep_x(const float* __restrict__ feat,
    u16* __restrict__ Xhi, u16* __restrict__ Xlo, float* __restrict__ xnorm) {
  __shared__ float sm[64][65];
  int b = blockIdx.x >> 4;
  int hw0 = (blockIdx.x & 15) << 6;
  int t = threadIdx.x;
  int hwi = t & 63, ci0 = t >> 6;
  float xs2[2] = {0.f, 0.f};
  int cj = t & 7;
  for (int c0 = 0; c0 < 512; c0 += 64) {
    for (int ci = ci0; ci < 64; ci += 4)
      sm[ci][hwi] = feat[((b * 512 + c0 + ci) << 10) + hw0 + hwi];
    __syncthreads();
    for (int w = 0; w < 2; ++w) {
      int hj = (t >> 3) + (w << 5);
      int n = (b << 10) + hw0 + hj;
      uint32_t hp[4], lp[4];
      for (int p = 0; p < 4; ++p) {
        float v0 = sm[cj * 8 + p * 2 + 0][hj];
        float v1 = sm[cj * 8 + p * 2 + 1][hj];
        xs2[w] += v0 * v0 + v1 * v1;
        u16 h0 = f2b(v0), h1 = f2b(v1);
        u16 l0 = f2b(v0 - b2f(h0)), l1 = f2b(v1 - b2f(h1));
        hp[p] = (uint32_t)h0 | ((uint32_t)h1 << 16);
        lp[p] = (uint32_t)l0 | ((uint32_t)l1 << 16);
      }
      *(uint4*)(Xhi + n * 512 + c0 + cj * 8) = make_uint4(hp[0], hp[1], hp[2], hp[3]);
      *(uint4*)(Xlo + n * 512 + c0 + cj * 8) = make_uint4(lp[0], lp[1], lp[2], lp[3]);
    }
    __syncthreads();
  }
  for (int w = 0; w < 2; ++w) {
    float v = xs2[w];
    v += __shfl_xor(v, 1); v += __shfl_xor(v, 2); v += __shfl_xor(v, 4);
    if (cj == 0) {
      int hj = (t >> 3) + (w << 5);
      xnorm[(b << 10) + hw0 + hj] = v;
    }
  }
}

// ---------------- prep: codebook -> Ehi/Elo + enorm (exact fp32) --------------
__global__ __launch_bounds__(64) void prep_e(const float* __restrict__ cb,
    u16* __restrict__ Ehi, u16* __restrict__ Elo, float* __restrict__ enorm) {
  int k = blockIdx.x, l = threadIdx.x;
  float nrm = 0.f;
  for (int it = 0; it < 2; ++it) {
    int c = (l + it * 64) * 4;
    float4 v = *(const float4*)(cb + k * 512 + c);
    nrm += v.x * v.x + v.y * v.y + v.z * v.z + v.w * v.w;
    u16 h0 = f2b(v.x), h1 = f2b(v.y), h2 = f2b(v.z), h3 = f2b(v.w);
    uint2 hp; hp.x = (uint32_t)h0 | ((uint32_t)h1 << 16);
    hp.y = (uint32_t)h2 | ((uint32_t)h3 << 16);
    *(uint2*)(Ehi + k * 512 + c) = hp;
    u16 q0 = f2b(v.x - b2f(h0)), q1 = f2b(v.y - b2f(h1));
    u16 q2 = f2b(v.z - b2f(h2)), q3 = f2b(v.w - b2f(h3));
    uint2 lq; lq.x = (uint32_t)q0 | ((uint32_t)q1 << 16);
    lq.y = (uint32_t)q2 | ((uint32_t)q3 << 16);
    *(uint2*)(Elo + k * 512 + c) = lq;
  }
  for (int o = 32; o; o >>= 1) nrm += __shfl_xor(nrm, o);
  if (l == 0) enorm[k] = nrm;
}

// ---------------- prep: Et[c][k] = bf16(codebook[k][c]) (for q GEMM) ----------
__global__ __launch_bounds__(256) void prep_et(const u16* __restrict__ Ehi, u16* __restrict__ Et) {
  __shared__ u16 sm[64][68];
  int k0 = (blockIdx.x & 63) << 6;
  int c0 = (blockIdx.x >> 6) << 6;
  int t = threadIdx.x;
  for (int idx = t; idx < 1024; idx += 256) {
    int ki = idx >> 4, cc = idx & 15;
    uint2 v = *(const uint2*)(Ehi + (k0 + ki) * 512 + c0 + cc * 4);
    *(uint2*)&sm[ki][cc * 4] = v;
  }
  __syncthreads();
  for (int idx = t; idx < 1024; idx += 256) {
    int ci = idx >> 4, kc = idx & 15;
    u16 a0 = sm[kc * 4 + 0][ci], a1 = sm[kc * 4 + 1][ci];
    u16 a2 = sm[kc * 4 + 2][ci], a3 = sm[kc * 4 + 3][ci];
    uint2 o; o.x = (uint32_t)a0 | ((uint32_t)a1 << 16);
    o.y = (uint32_t)a2 | ((uint32_t)a3 << 16);
    *(uint2*)(Et + (c0 + ci) * 4096 + k0 + kc * 4) = o;
  }
}

// ================= GEMM1: 256x256 tile, BK=64, 8 waves, 8-phase ===============
// Epilogue also emits per-(row, col-tile) partial softmax sums using the
// xnorm-shift trick: l = xnorm - d = 2*acc - enorm (no max needed).
__device__ __forceinline__ void stageA_g1(const u16* __restrict__ g, u16* l, int h, int t) {
  int r0 = t >> 3, c = ((t & 7) ^ (r0 & 7)) * 8, cw = (t & 7) * 8;
  int ra = h * 64 + r0, rb = 128 + h * 64 + r0;
  g2l16(g + ra * 512 + c, l + ra * 64 + cw);
  g2l16(g + rb * 512 + c, l + rb * 64 + cw);
}
__device__ __forceinline__ void stageB_g1(const u16* __restrict__ g, u16* l, int hb, int t) {
  int r0 = t >> 3, c = ((t & 7) ^ (r0 & 7)) * 8, cw = (t & 7) * 8;
  int ra = (r0 >> 5) * 64 + hb * 32 + (r0 & 31);
  int rb = ((r0 + 64) >> 5) * 64 + hb * 32 + (r0 & 31);
  g2l16(g + ra * 512 + c, l + ra * 64 + cw);
  g2l16(g + rb * 512 + c, l + rb * 64 + cw);
}

template<int Q>
__device__ __forceinline__ void phase_ld(const u16* Ab, const u16* Bb,
    int wm, int wn, int lane16, int kl, bf16x8 (&af)[4][2], bf16x8 (&bf2)[2][2]) {
  int sw = lane16 & 7;
  if constexpr (Q == 0 || Q == 2) {
#pragma unroll
    for (int m = 0; m < 4; ++m)
#pragma unroll
      for (int s = 0; s < 2; ++s)
        af[m][s] = *(const bf16x8*)(Ab + (wm * 128 + ((Q >> 1) * 4 + m) * 16 + lane16) * 64
                                    + (((s * 4 + kl) ^ sw) * 8));
  }
  if constexpr (Q != 2) {
    constexpr int NF0 = (Q == 1) ? 2 : 0;
#pragma unroll
    for (int n = 0; n < 2; ++n)
#pragma unroll
      for (int s = 0; s < 2; ++s)
        bf2[n][s] = *(const bf16x8*)(Bb + (wn * 64 + (NF0 + n) * 16 + lane16) * 64
                                     + (((s * 4 + kl) ^ sw) * 8));
  }
}
template<int Q>
__device__ __forceinline__ void phase_mm(bf16x8 (&af)[4][2], bf16x8 (&bf2)[2][2],
                                         f32x4 (&acc)[8][4]) {
  constexpr int MQ = (Q >> 1) * 4;
  constexpr int NF0 = (Q == 1 || Q == 2) ? 2 : 0;
#pragma unroll
  for (int m = 0; m < 4; ++m)
#pragma unroll
    for (int n = 0; n < 2; ++n)
#pragma unroll
      for (int s = 0; s < 2; ++s)
        acc[MQ + m][NF0 + n] = __builtin_amdgcn_mfma_f32_16x16x32_bf16(
            af[m][s], bf2[n][s], acc[MQ + m][NF0 + n], 0, 0, 0);
}

#define FENCE() asm volatile("" ::: "memory")
#define BAR() __builtin_amdgcn_s_barrier()
#define VMW4() asm volatile("s_waitcnt vmcnt(4)" ::: "memory")
#define VMW0() asm volatile("s_waitcnt vmcnt(0)" ::: "memory")

__global__ __launch_bounds__(512, 2) void gemm1_8ph(const u16* __restrict__ Xhi,
    const u16* __restrict__ Xlo, const u16* __restrict__ Ehi, const u16* __restrict__ Elo,
    const float* __restrict__ xnorm, const float* __restrict__ enorm,
    float* __restrict__ D, float* __restrict__ S1p, float* __restrict__ STp) {
  __shared__ __align__(16) u16 lds[2][2][256 * 64];  // 128 KB
  int bid = blockIdx.x;
  int s = (bid & 7) * 128 + (bid >> 3);   // XCD swizzle, bijective (1024 % 8 == 0)
  int rt = s >> 4, ct = s & 15;
  int n0 = rt << 8, k0 = ct << 8;
  int t = threadIdx.x;
  int l = t & 63, w = t >> 6;
  int wm = w >> 2, wn = w & 3;
  int lane16 = l & 15, kl = l >> 4;

  u16* lA0 = &lds[0][0][0]; u16* lB0 = &lds[0][1][0];
  u16* lA1 = &lds[1][0][0]; u16* lB1 = &lds[1][1][0];

  auto gA = [&](int kt) { return ((kt >> 3) == 1 ? Xlo : Xhi) + n0 * 512 + (kt & 7) * 64; };
  auto gB = [&](int kt) { return ((kt >> 3) == 2 ? Elo : Ehi) + k0 * 512 + (kt & 7) * 64; };

  f32x4 acc[8][4];
#pragma unroll
  for (int m = 0; m < 8; ++m)
#pragma unroll
    for (int n = 0; n < 4; ++n) acc[m][n] = f32x4{0.f, 0.f, 0.f, 0.f};
  bf16x8 af[4][2], bf2[2][2];

  stageA_g1(gA(0), lA0, 0, t);
  stageB_g1(gB(0), lB0, 1, t);
  stageB_g1(gB(0), lB0, 0, t);
  stageA_g1(gA(0), lA0, 1, t);
  stageA_g1(gA(1), lA1, 0, t);
  stageB_g1(gB(1), lB1, 1, t);
  VMW4();
  BAR();

#pragma unroll 1
  for (int i = 0; i < 12; ++i) {
    int ktO = 2 * i + 1;
    int ktE2 = 2 * i + 2, ktO2 = 2 * i + 3;
    bool more = (i < 11);
    phase_ld<0>(lA0, lB0, wm, wn, lane16, kl, af, bf2);
    stageB_g1(gB(ktO), lB1, 0, t);
    FENCE(); BAR();
    __builtin_amdgcn_s_setprio(1); phase_mm<0>(af, bf2, acc); __builtin_amdgcn_s_setprio(0);
    FENCE(); BAR();
    phase_ld<1>(lA0, lB0, wm, wn, lane16, kl, af, bf2);
    stageA_g1(gA(ktO), lA1, 1, t);
    FENCE(); BAR();
    __builtin_amdgcn_s_setprio(1); phase_mm<1>(af, bf2, acc); __builtin_amdgcn_s_setprio(0);
    FENCE(); BAR();
    phase_ld<2>(lA0, lB0, wm, wn, lane16, kl, af, bf2);
    if (more) stageA_g1(gA(ktE2), lA0, 0, t);
    FENCE(); BAR();
    __builtin_amdgcn_s_setprio(1); phase_mm<2>(af, bf2, acc); __builtin_amdgcn_s_setprio(0);
    FENCE(); BAR();
    phase_ld<3>(lA0, lB0, wm, wn, lane16, kl, af, bf2);
    if (more) stageB_g1(gB(ktE2), lB0, 1, t);
    FENCE(); BAR();
    __builtin_amdgcn_s_setprio(1); phase_mm<3>(af, bf2, acc); __builtin_amdgcn_s_setprio(0);
    if (i == 11) { VMW0(); } else { VMW4(); }
    BAR();
    phase_ld<0>(lA1, lB1, wm, wn, lane16, kl, af, bf2);
    if (more) stageB_g1(gB(ktE2), lB0, 0, t);
    FENCE(); BAR();
    __builtin_amdgcn_s_setprio(1); phase_mm<0>(af, bf2, acc); __builtin_amdgcn_s_setprio(0);
    FENCE(); BAR();
    phase_ld<1>(lA1, lB1, wm, wn, lane16, kl, af, bf2);
    if (more) stageA_g1(gA(ktE2), lA0, 1, t);
    FENCE(); BAR();
    __builtin_amdgcn_s_setprio(1); phase_mm<1>(af, bf2, acc); __builtin_amdgcn_s_setprio(0);
    FENCE(); BAR();
    phase_ld<2>(lA1, lB1, wm, wn, lane16, kl, af, bf2);
    if (more) stageA_g1(gA(ktO2), lA1, 0, t);
    FENCE(); BAR();
    __builtin_amdgcn_s_setprio(1); phase_mm<2>(af, bf2, acc); __builtin_amdgcn_s_setprio(0);
    FENCE(); BAR();
    phase_ld<3>(lA1, lB1, wm, wn, lane16, kl, af, bf2);
    if (more) stageB_g1(gB(ktO2), lB1, 1, t);
    FENCE(); BAR();
    __builtin_amdgcn_s_setprio(1); phase_mm<3>(af, bf2, acc); __builtin_amdgcn_s_setprio(0);
    if (more) { VMW4(); }
    BAR();
  }

  // ---- epilogue: D = xnorm - l  (l = 2*acc - enorm), plus partial exp-sums ----
  float en[4];
#pragma unroll
  for (int nf = 0; nf < 4; ++nf) en[nf] = enorm[k0 + wn * 64 + nf * 16 + lane16];
  float* ldsS = (float*)&lds[0][0][0];   // [256][4]
  float* ldsT = ldsS + 1024;             // [256][4]
#pragma unroll
  for (int mf = 0; mf < 8; ++mf) {
#pragma unroll
    for (int r = 0; r < 4; ++r) {
      int lrow = wm * 128 + mf * 16 + kl * 4 + r;
      int row = n0 + lrow;
      float xv = xnorm[row];
      float lv[4];
#pragma unroll
      for (int nf = 0; nf < 4; ++nf) lv[nf] = 2.0f * acc[mf][nf][r] - en[nf];
      float* Drow = D + (size_t)row * 4096 + k0 + wn * 64 + lane16;
#pragma unroll
      for (int nf = 0; nf < 4; ++nf) Drow[nf * 16] = xv - lv[nf];
      float s1 = __expf(lv[0]) + __expf(lv[1]) + __expf(lv[2]) + __expf(lv[3]);
      float sT = __expf(lv[0] * INVT - CSH) + __expf(lv[1] * INVT - CSH)
               + __expf(lv[2] * INVT - CSH) + __expf(lv[3] * INVT - CSH);
#pragma unroll
      for (int o = 1; o < 16; o <<= 1) { s1 += __shfl_xor(s1, o); sT += __shfl_xor(sT, o); }
      if (lane16 == 0) { ldsS[lrow * 4 + wn] = s1; ldsT[lrow * 4 + wn] = sT; }
    }
  }
  __syncthreads();
  {
    int rr = t & 255;
    if (t < 256) {
      float v = ldsS[rr * 4 + 0] + ldsS[rr * 4 + 1] + ldsS[rr * 4 + 2] + ldsS[rr * 4 + 3];
      S1p[ct * 16384 + n0 + rr] = v;
    } else {
      float v = ldsT[rr * 4 + 0] + ldsT[rr * 4 + 1] + ldsT[rr * 4 + 2] + ldsT[rr * 4 + 3];
      STp[ct * 16384 + n0 + rr] = v;
    }
  }
}

// ------- softmax outputs: combine partials (cheap) + single D pass ------------
__global__ __launch_bounds__(256) void softmax_out(const float* __restrict__ D,
    const float* __restrict__ xnorm, const float* __restrict__ S1p,
    const float* __restrict__ STp, float* __restrict__ assign, u16* __restrict__ P) {
  __shared__ float tt[128][33];
  int n0 = blockIdx.x << 5;
  int b = n0 >> 10, hw0 = n0 & 1023;
  int t = threadIdx.x;
  int i = t >> 3, jc = t & 7;
  int row = n0 + i;
  const float* Dr = D + (size_t)row * 4096;
  float s1 = S1p[(jc * 2) * 16384 + row] + S1p[(jc * 2 + 1) * 16384 + row];
  float sT = STp[(jc * 2) * 16384 + row] + STp[(jc * 2 + 1) * 16384 + row];
#pragma unroll
  for (int o = 1; o < 8; o <<= 1) { s1 += __shfl_xor(s1, o); sT += __shfl_xor(sT, o); }
  float is1 = 1.0f / s1, isT = 1.0f / sT;
  float xn = xnorm[row];

  float* assignB = assign + b * 4194304 + hw0;
  u16* Pr = P + (size_t)row * 4096;
  for (int kt = 0; kt < 32; ++kt) {
    int kb = kt << 7;
    for (int it = 0; it < 4; ++it) {
      int col4 = (jc + it * 8) * 4;
      float4 dv = *(const float4*)(Dr + kb + col4);
      float e0 = xn - dv.x, e1 = xn - dv.y, e2 = xn - dv.z, e3 = xn - dv.w;
      u16 p0 = f2b(__expf(e0) * is1), p1 = f2b(__expf(e1) * is1);
      u16 p2 = f2b(__expf(e2) * is1), p3 = f2b(__expf(e3) * is1);
      uint2 pp; pp.x = (uint32_t)p0 | ((uint32_t)p1 << 16);
      pp.y = (uint32_t)p2 | ((uint32_t)p3 << 16);
      *(uint2*)(Pr + kb + col4) = pp;
      tt[col4 + 0][i] = __expf(e0 * INVT - CSH) * isT;
      tt[col4 + 1][i] = __expf(e1 * INVT - CSH) * isT;
      tt[col4 + 2][i] = __expf(e2 * INVT - CSH) * isT;
      tt[col4 + 3][i] = __expf(e3 * INVT - CSH) * isT;
    }
    __syncthreads();
    for (int idx = t; idx < 1024; idx += 256) {
      int j = idx >> 3, ic = idx & 7;
      float4 o;
      o.x = tt[j][ic * 4 + 0]; o.y = tt[j][ic * 4 + 1];
      o.z = tt[j][ic * 4 + 2]; o.w = tt[j][ic * 4 + 3];
      *(float4*)(assignB + (kb + j) * 1024 + ic * 4) = o;
    }
    __syncthreads();
  }
}

// ---------------- GEMM2: q^T = Et (c x K) . P^T  -> (b, c, hw) directly -------
__global__ __launch_bounds__(256) void gemm2(const u16* __restrict__ Et,
    const u16* __restrict__ P, float* __restrict__ Q) {
  __shared__ u16 As[2][128 * 32];
  __shared__ u16 Bs[2][128 * 32];
  int bid = blockIdx.x;
  int s = (bid & 7) * 64 + (bid >> 3);
  int rt = s >> 7, ct = s & 127;
  int c0 = rt << 7, n0 = ct << 7;
  int t = threadIdx.x;
  auto stage = [&](int buf, int cc) {
    int cin = cc << 5;
    for (int i = 0; i < 2; ++i) {
      int idx = i * 256 + t;
      int row = idx >> 2, chv = idx & 3;
      g2l16(Et + (c0 + row) * 4096 + cin + chv * 8, &As[buf][idx * 8]);
      g2l16(P + (n0 + row) * 4096 + cin + chv * 8, &Bs[buf][idx * 8]);
    }
  };
  int l = t & 63, w = t >> 6;
  int wr = (w >> 1) << 6, wc = (w & 1) << 6;
  int lane16 = l & 15, kl = l >> 4;
  f32x4 acc[4][4];
  for (int m = 0; m < 4; ++m)
    for (int nn = 0; nn < 4; ++nn) acc[m][nn] = f32x4{0.f, 0.f, 0.f, 0.f};
  stage(0, 0);
  __syncthreads();
  for (int cc = 0; cc < 128; ++cc) {
    int buf = cc & 1;
    if (cc + 1 < 128) stage(buf ^ 1, cc + 1);
    bf16x8 af[4], bfr[4];
    for (int m = 0; m < 4; ++m)
      af[m] = *(const bf16x8*)&As[buf][(wr + m * 16 + lane16) * 32 + kl * 8];
    for (int nn = 0; nn < 4; ++nn)
      bfr[nn] = *(const bf16x8*)&Bs[buf][(wc + nn * 16 + lane16) * 32 + kl * 8];
    for (int m = 0; m < 4; ++m)
      for (int nn = 0; nn < 4; ++nn)
        acc[m][nn] = __builtin_amdgcn_mfma_f32_16x16x32_bf16(af[m], bfr[nn], acc[m][nn], 0, 0, 0);
    __syncthreads();
  }
  for (int m = 0; m < 4; ++m) {
    for (int r = 0; r < 4; ++r) {
      int crow = c0 + wr + m * 16 + kl * 4 + r;
      for (int nn = 0; nn < 4; ++nn) {
        int col = n0 + wc + nn * 16 + lane16;
        int bb = col >> 10, hw = col & 1023;
        Q[bb * 524288 + crow * 1024 + hw] = acc[m][nn][r];
      }
    }
  }
}

extern "C" void kernel_launch(void* const* d_in, const int* in_sizes, int n_in,
                              void* d_out, int out_size, void* d_ws, size_t ws_size,
                              hipStream_t stream) {
  const float* feat = (const float*)d_in[0];   // (16, 512, 32, 32)
  const float* cb = (const float*)d_in[1];     // (4096, 512)
  float* out = (float*)d_out;
  float* q_out = out;                          // 8388608
  float* a_out = out + 8388608;                // 67108864
  float* d_dist = out + 75497472;              // 67108864

  char* ws = (char*)d_ws;
  u16* Xhi = (u16*)(ws + 0);                   // 16 MB
  u16* Xlo = (u16*)(ws + 16777216);            // 16 MB
  u16* Ehi = (u16*)(ws + 33554432);            // 4 MB
  u16* Elo = (u16*)(ws + 37748736);            // 4 MB
  u16* Et  = (u16*)(ws + 41943040);            // 4 MB
  float* xnorm = (float*)(ws + 46137344);      // 64 KB
  float* enorm = (float*)(ws + 46202880);      // 16 KB
  float* S1p = (float*)(ws + 46219264);        // 1 MB  [16][16384]
  float* STp = (float*)(ws + 47267840);        // 1 MB
  u16* P = (u16*)(ws + 48316416);              // 128 MB -> ends ~182.5 MB

  prep_x<<<256, 256, 0, stream>>>(feat, Xhi, Xlo, xnorm);
  prep_e<<<4096, 64, 0, stream>>>(cb, Ehi, Elo, enorm);
  prep_et<<<512, 256, 0, stream>>>(Ehi, Et);
  gemm1_8ph<<<1024, 512, 0, stream>>>(Xhi, Xlo, Ehi, Elo, xnorm, enorm, d_dist, S1p, STp);
  softmax_out<<<512, 256, 0, stream>>>(d_dist, xnorm, S1p, STp, a_out, P);
  gemm2<<<512, 256, 0, stream>>>(Et, P, q_out);
}

// Round 5
// 424.149 us; speedup vs baseline: 1.4775x; 1.2536x over previous
//
#include <hip/hip_runtime.h>
#include <hip/hip_bf16.h>
#include <stdint.h>

typedef unsigned short u16;
typedef _Float16 f16;
typedef f16 f16x8 __attribute__((ext_vector_type(8)));
typedef __bf16 bf16x8 __attribute__((ext_vector_type(8)));
typedef float f32x4 __attribute__((ext_vector_type(4)));

#define INVT 14.2857142857142857f  // 1/0.07
#define CSH  32.0f                 // extra shift on T-path exponents (softmax-invariant)

__device__ __forceinline__ u16 f2b(float f) {
  __hip_bfloat16 h = __float2bfloat16(f);
  return __builtin_bit_cast(u16, h);
}
__device__ __forceinline__ u16 f2h(float f) {
  f16 h = (f16)f;
  return __builtin_bit_cast(u16, h);
}
__device__ __forceinline__ void g2l16(const void* g, void* l) {
  __builtin_amdgcn_global_load_lds(
      (__attribute__((address_space(1))) void*)(uintptr_t)g,
      (__attribute__((address_space(3))) void*)(uint32_t)(uintptr_t)l, 16, 0, 0);
}

// ---- prep: feat (b,c,hw) -> X fp16 (n, c), n = b*1024+hw; + xnorm (fp32) -----
__global__ __launch_bounds__(256) void prep_x(const float* __restrict__ feat,
    u16* __restrict__ Xh, float* __restrict__ xnorm) {
  __shared__ float sm[64][65];
  int b = blockIdx.x >> 4;
  int hw0 = (blockIdx.x & 15) << 6;
  int t = threadIdx.x;
  int hwi = t & 63, ci0 = t >> 6;
  float xs2[2] = {0.f, 0.f};
  int cj = t & 7;
  for (int c0 = 0; c0 < 512; c0 += 64) {
    for (int ci = ci0; ci < 64; ci += 4)
      sm[ci][hwi] = feat[((b * 512 + c0 + ci) << 10) + hw0 + hwi];
    __syncthreads();
    for (int w = 0; w < 2; ++w) {
      int hj = (t >> 3) + (w << 5);
      int n = (b << 10) + hw0 + hj;
      uint32_t hp[4];
      for (int p = 0; p < 4; ++p) {
        float v0 = sm[cj * 8 + p * 2 + 0][hj];
        float v1 = sm[cj * 8 + p * 2 + 1][hj];
        xs2[w] += v0 * v0 + v1 * v1;
        hp[p] = (uint32_t)f2h(v0) | ((uint32_t)f2h(v1) << 16);
      }
      *(uint4*)(Xh + n * 512 + c0 + cj * 8) = make_uint4(hp[0], hp[1], hp[2], hp[3]);
    }
    __syncthreads();
  }
  for (int w = 0; w < 2; ++w) {
    float v = xs2[w];
    v += __shfl_xor(v, 1); v += __shfl_xor(v, 2); v += __shfl_xor(v, 4);
    if (cj == 0) {
      int hj = (t >> 3) + (w << 5);
      xnorm[(b << 10) + hw0 + hj] = v;
    }
  }
}

// ---------------- prep: codebook -> E fp16 + enorm (exact fp32) ---------------
__global__ __launch_bounds__(64) void prep_e(const float* __restrict__ cb,
    u16* __restrict__ Eh, float* __restrict__ enorm) {
  int k = blockIdx.x, l = threadIdx.x;
  float nrm = 0.f;
  for (int it = 0; it < 2; ++it) {
    int c = (l + it * 64) * 4;
    float4 v = *(const float4*)(cb + k * 512 + c);
    nrm += v.x * v.x + v.y * v.y + v.z * v.z + v.w * v.w;
    uint2 hp;
    hp.x = (uint32_t)f2h(v.x) | ((uint32_t)f2h(v.y) << 16);
    hp.y = (uint32_t)f2h(v.z) | ((uint32_t)f2h(v.w) << 16);
    *(uint2*)(Eh + k * 512 + c) = hp;
  }
  for (int o = 32; o; o >>= 1) nrm += __shfl_xor(nrm, o);
  if (l == 0) enorm[k] = nrm;
}

// ------------ prep: Et[c][k] = bf16(codebook[k][c]) (for q GEMM) --------------
__global__ __launch_bounds__(256) void prep_et(const float* __restrict__ cb, u16* __restrict__ Et) {
  __shared__ u16 sm[64][68];
  int k0 = (blockIdx.x & 63) << 6;
  int c0 = (blockIdx.x >> 6) << 6;
  int t = threadIdx.x;
  for (int idx = t; idx < 1024; idx += 256) {
    int ki = idx >> 4, cc = idx & 15;
    float4 v = *(const float4*)(cb + (k0 + ki) * 512 + c0 + cc * 4);
    uint2 o;
    o.x = (uint32_t)f2b(v.x) | ((uint32_t)f2b(v.y) << 16);
    o.y = (uint32_t)f2b(v.z) | ((uint32_t)f2b(v.w) << 16);
    *(uint2*)&sm[ki][cc * 4] = o;
  }
  __syncthreads();
  for (int idx = t; idx < 1024; idx += 256) {
    int ci = idx >> 4, kc = idx & 15;
    u16 a0 = sm[kc * 4 + 0][ci], a1 = sm[kc * 4 + 1][ci];
    u16 a2 = sm[kc * 4 + 2][ci], a3 = sm[kc * 4 + 3][ci];
    uint2 o; o.x = (uint32_t)a0 | ((uint32_t)a1 << 16);
    o.y = (uint32_t)a2 | ((uint32_t)a3 << 16);
    *(uint2*)(Et + (c0 + ci) * 4096 + k0 + kc * 4) = o;
  }
}

// ============ GEMM1 (fp16): 256x256 tile, BK=64, 8 waves, 8-phase =============
// D = xnorm + enorm - 2*(X.E), K = 512 = 8 Ktiles (4 pair-iterations).
__device__ __forceinline__ void stageA_g1(const u16* __restrict__ g, u16* l, int h, int t) {
  int r0 = t >> 3, c = ((t & 7) ^ (r0 & 7)) * 8, cw = (t & 7) * 8;
  int ra = h * 64 + r0, rb = 128 + h * 64 + r0;
  g2l16(g + ra * 512 + c, l + ra * 64 + cw);
  g2l16(g + rb * 512 + c, l + rb * 64 + cw);
}
__device__ __forceinline__ void stageB_g1(const u16* __restrict__ g, u16* l, int hb, int t) {
  int r0 = t >> 3, c = ((t & 7) ^ (r0 & 7)) * 8, cw = (t & 7) * 8;
  int ra = (r0 >> 5) * 64 + hb * 32 + (r0 & 31);
  int rb = ((r0 + 64) >> 5) * 64 + hb * 32 + (r0 & 31);
  g2l16(g + ra * 512 + c, l + ra * 64 + cw);
  g2l16(g + rb * 512 + c, l + rb * 64 + cw);
}

template<int Q>
__device__ __forceinline__ void phase_ld(const u16* Ab, const u16* Bb,
    int wm, int wn, int lane16, int kl, f16x8 (&af)[4][2], f16x8 (&bf2)[2][2]) {
  int sw = lane16 & 7;
  if constexpr (Q == 0 || Q == 2) {
#pragma unroll
    for (int m = 0; m < 4; ++m)
#pragma unroll
      for (int s = 0; s < 2; ++s)
        af[m][s] = *(const f16x8*)(Ab + (wm * 128 + ((Q >> 1) * 4 + m) * 16 + lane16) * 64
                                   + (((s * 4 + kl) ^ sw) * 8));
  }
  if constexpr (Q != 2) {
    constexpr int NF0 = (Q == 1) ? 2 : 0;
#pragma unroll
    for (int n = 0; n < 2; ++n)
#pragma unroll
      for (int s = 0; s < 2; ++s)
        bf2[n][s] = *(const f16x8*)(Bb + (wn * 64 + (NF0 + n) * 16 + lane16) * 64
                                    + (((s * 4 + kl) ^ sw) * 8));
  }
}
template<int Q>
__device__ __forceinline__ void phase_mm(f16x8 (&af)[4][2], f16x8 (&bf2)[2][2],
                                         f32x4 (&acc)[8][4]) {
  constexpr int MQ = (Q >> 1) * 4;
  constexpr int NF0 = (Q == 1 || Q == 2) ? 2 : 0;
#pragma unroll
  for (int m = 0; m < 4; ++m)
#pragma unroll
    for (int n = 0; n < 2; ++n)
#pragma unroll
      for (int s = 0; s < 2; ++s)
        acc[MQ + m][NF0 + n] = __builtin_amdgcn_mfma_f32_16x16x32_f16(
            af[m][s], bf2[n][s], acc[MQ + m][NF0 + n], 0, 0, 0);
}

#define FENCE() asm volatile("" ::: "memory")
#define BAR() __builtin_amdgcn_s_barrier()
#define VMW4() asm volatile("s_waitcnt vmcnt(4)" ::: "memory")
#define VMW0() asm volatile("s_waitcnt vmcnt(0)" ::: "memory")

__global__ __launch_bounds__(512, 2) void gemm1_8ph(const u16* __restrict__ Xh,
    const u16* __restrict__ Eh, const float* __restrict__ xnorm,
    const float* __restrict__ enorm, float* __restrict__ D,
    float* __restrict__ S1p, float* __restrict__ STp) {
  __shared__ __align__(16) u16 lds[2][2][256 * 64];  // 128 KB
  int bid = blockIdx.x;
  int s = (bid & 7) * 128 + (bid >> 3);   // XCD swizzle, bijective (1024 % 8 == 0)
  int rt = s >> 4, ct = s & 15;
  int n0 = rt << 8, k0 = ct << 8;
  int t = threadIdx.x;
  int l = t & 63, w = t >> 6;
  int wm = w >> 2, wn = w & 3;
  int lane16 = l & 15, kl = l >> 4;

  u16* lA0 = &lds[0][0][0]; u16* lB0 = &lds[0][1][0];
  u16* lA1 = &lds[1][0][0]; u16* lB1 = &lds[1][1][0];

  auto gA = [&](int kt) { return Xh + n0 * 512 + kt * 64; };
  auto gB = [&](int kt) { return Eh + k0 * 512 + kt * 64; };

  f32x4 acc[8][4];
#pragma unroll
  for (int m = 0; m < 8; ++m)
#pragma unroll
    for (int n = 0; n < 4; ++n) acc[m][n] = f32x4{0.f, 0.f, 0.f, 0.f};
  f16x8 af[4][2], bf2[2][2];

  stageA_g1(gA(0), lA0, 0, t);
  stageB_g1(gB(0), lB0, 1, t);
  stageB_g1(gB(0), lB0, 0, t);
  stageA_g1(gA(0), lA0, 1, t);
  stageA_g1(gA(1), lA1, 0, t);
  stageB_g1(gB(1), lB1, 1, t);
  VMW4();
  BAR();

#pragma unroll 1
  for (int i = 0; i < 4; ++i) {
    int ktO = 2 * i + 1;
    int ktE2 = 2 * i + 2, ktO2 = 2 * i + 3;
    bool more = (i < 3);
    phase_ld<0>(lA0, lB0, wm, wn, lane16, kl, af, bf2);
    stageB_g1(gB(ktO), lB1, 0, t);
    FENCE(); BAR();
    __builtin_amdgcn_s_setprio(1); phase_mm<0>(af, bf2, acc); __builtin_amdgcn_s_setprio(0);
    FENCE(); BAR();
    phase_ld<1>(lA0, lB0, wm, wn, lane16, kl, af, bf2);
    stageA_g1(gA(ktO), lA1, 1, t);
    FENCE(); BAR();
    __builtin_amdgcn_s_setprio(1); phase_mm<1>(af, bf2, acc); __builtin_amdgcn_s_setprio(0);
    FENCE(); BAR();
    phase_ld<2>(lA0, lB0, wm, wn, lane16, kl, af, bf2);
    if (more) stageA_g1(gA(ktE2), lA0, 0, t);
    FENCE(); BAR();
    __builtin_amdgcn_s_setprio(1); phase_mm<2>(af, bf2, acc); __builtin_amdgcn_s_setprio(0);
    FENCE(); BAR();
    phase_ld<3>(lA0, lB0, wm, wn, lane16, kl, af, bf2);
    if (more) stageB_g1(gB(ktE2), lB0, 1, t);
    FENCE(); BAR();
    __builtin_amdgcn_s_setprio(1); phase_mm<3>(af, bf2, acc); __builtin_amdgcn_s_setprio(0);
    if (i == 3) { VMW0(); } else { VMW4(); }
    BAR();
    phase_ld<0>(lA1, lB1, wm, wn, lane16, kl, af, bf2);
    if (more) stageB_g1(gB(ktE2), lB0, 0, t);
    FENCE(); BAR();
    __builtin_amdgcn_s_setprio(1); phase_mm<0>(af, bf2, acc); __builtin_amdgcn_s_setprio(0);
    FENCE(); BAR();
    phase_ld<1>(lA1, lB1, wm, wn, lane16, kl, af, bf2);
    if (more) stageA_g1(gA(ktE2), lA0, 1, t);
    FENCE(); BAR();
    __builtin_amdgcn_s_setprio(1); phase_mm<1>(af, bf2, acc); __builtin_amdgcn_s_setprio(0);
    FENCE(); BAR();
    phase_ld<2>(lA1, lB1, wm, wn, lane16, kl, af, bf2);
    if (more) stageA_g1(gA(ktO2), lA1, 0, t);
    FENCE(); BAR();
    __builtin_amdgcn_s_setprio(1); phase_mm<2>(af, bf2, acc); __builtin_amdgcn_s_setprio(0);
    FENCE(); BAR();
    phase_ld<3>(lA1, lB1, wm, wn, lane16, kl, af, bf2);
    if (more) stageB_g1(gB(ktO2), lB1, 1, t);
    FENCE(); BAR();
    __builtin_amdgcn_s_setprio(1); phase_mm<3>(af, bf2, acc); __builtin_amdgcn_s_setprio(0);
    if (more) { VMW4(); }
    BAR();
  }

  // ---- epilogue: D = xnorm - l  (l = 2*acc - enorm), plus partial exp-sums ----
  float en[4];
#pragma unroll
  for (int nf = 0; nf < 4; ++nf) en[nf] = enorm[k0 + wn * 64 + nf * 16 + lane16];
  float* ldsS = (float*)&lds[0][0][0];   // [256][4]
  float* ldsT = ldsS + 1024;             // [256][4]
#pragma unroll
  for (int mf = 0; mf < 8; ++mf) {
#pragma unroll
    for (int r = 0; r < 4; ++r) {
      int lrow = wm * 128 + mf * 16 + kl * 4 + r;
      int row = n0 + lrow;
      float xv = xnorm[row];
      float lv[4];
#pragma unroll
      for (int nf = 0; nf < 4; ++nf) lv[nf] = 2.0f * acc[mf][nf][r] - en[nf];
      float* Drow = D + (size_t)row * 4096 + k0 + wn * 64 + lane16;
#pragma unroll
      for (int nf = 0; nf < 4; ++nf) Drow[nf * 16] = xv - lv[nf];
      float s1 = __expf(lv[0]) + __expf(lv[1]) + __expf(lv[2]) + __expf(lv[3]);
      float sT = __expf(lv[0] * INVT - CSH) + __expf(lv[1] * INVT - CSH)
               + __expf(lv[2] * INVT - CSH) + __expf(lv[3] * INVT - CSH);
#pragma unroll
      for (int o = 1; o < 16; o <<= 1) { s1 += __shfl_xor(s1, o); sT += __shfl_xor(sT, o); }
      if (lane16 == 0) { ldsS[lrow * 4 + wn] = s1; ldsT[lrow * 4 + wn] = sT; }
    }
  }
  __syncthreads();
  {
    int rr = t & 255;
    if (t < 256) {
      float v = ldsS[rr * 4 + 0] + ldsS[rr * 4 + 1] + ldsS[rr * 4 + 2] + ldsS[rr * 4 + 3];
      S1p[ct * 16384 + n0 + rr] = v;
    } else {
      float v = ldsT[rr * 4 + 0] + ldsT[rr * 4 + 1] + ldsT[rr * 4 + 2] + ldsT[rr * 4 + 3];
      STp[ct * 16384 + n0 + rr] = v;
    }
  }
}

// ------- softmax outputs: combine partials (cheap) + single D pass ------------
__global__ __launch_bounds__(256) void softmax_out(const float* __restrict__ D,
    const float* __restrict__ xnorm, const float* __restrict__ S1p,
    const float* __restrict__ STp, float* __restrict__ assign, u16* __restrict__ P) {
  __shared__ float tt[128][33];
  int n0 = blockIdx.x << 5;
  int b = n0 >> 10, hw0 = n0 & 1023;
  int t = threadIdx.x;
  int i = t >> 3, jc = t & 7;
  int row = n0 + i;
  const float* Dr = D + (size_t)row * 4096;
  float s1 = S1p[(jc * 2) * 16384 + row] + S1p[(jc * 2 + 1) * 16384 + row];
  float sT = STp[(jc * 2) * 16384 + row] + STp[(jc * 2 + 1) * 16384 + row];
#pragma unroll
  for (int o = 1; o < 8; o <<= 1) { s1 += __shfl_xor(s1, o); sT += __shfl_xor(sT, o); }
  float is1 = 1.0f / s1, isT = 1.0f / sT;
  float xn = xnorm[row];

  float* assignB = assign + b * 4194304 + hw0;
  u16* Pr = P + (size_t)row * 4096;
  for (int kt = 0; kt < 32; ++kt) {
    int kb = kt << 7;
    for (int it = 0; it < 4; ++it) {
      int col4 = (jc + it * 8) * 4;
      float4 dv = *(const float4*)(Dr + kb + col4);
      float e0 = xn - dv.x, e1 = xn - dv.y, e2 = xn - dv.z, e3 = xn - dv.w;
      u16 p0 = f2b(__expf(e0) * is1), p1 = f2b(__expf(e1) * is1);
      u16 p2 = f2b(__expf(e2) * is1), p3 = f2b(__expf(e3) * is1);
      uint2 pp; pp.x = (uint32_t)p0 | ((uint32_t)p1 << 16);
      pp.y = (uint32_t)p2 | ((uint32_t)p3 << 16);
      *(uint2*)(Pr + kb + col4) = pp;
      tt[col4 + 0][i] = __expf(e0 * INVT - CSH) * isT;
      tt[col4 + 1][i] = __expf(e1 * INVT - CSH) * isT;
      tt[col4 + 2][i] = __expf(e2 * INVT - CSH) * isT;
      tt[col4 + 3][i] = __expf(e3 * INVT - CSH) * isT;
    }
    __syncthreads();
    for (int idx = t; idx < 1024; idx += 256) {
      int j = idx >> 3, ic = idx & 7;
      float4 o;
      o.x = tt[j][ic * 4 + 0]; o.y = tt[j][ic * 4 + 1];
      o.z = tt[j][ic * 4 + 2]; o.w = tt[j][ic * 4 + 3];
      *(float4*)(assignB + (kb + j) * 1024 + ic * 4) = o;
    }
    __syncthreads();
  }
}

// ---------------- GEMM2: q^T = Et (c x K) . P^T  -> (b, c, hw) directly -------
// XCD decode: ct = s>>2, rt = s&3 -> a P panel's 4 readers are s-adjacent in
// the SAME XCD -> L2 reuse instead of 4x HBM refetch.
__global__ __launch_bounds__(256) void gemm2(const u16* __restrict__ Et,
    const u16* __restrict__ P, float* __restrict__ Q) {
  __shared__ u16 As[2][128 * 32];
  __shared__ u16 Bs[2][128 * 32];
  int bid = blockIdx.x;
  int s = (bid & 7) * 64 + (bid >> 3);
  int ct = s >> 2, rt = s & 3;
  int c0 = rt << 7, n0 = ct << 7;
  int t = threadIdx.x;
  auto stage = [&](int buf, int cc) {
    int cin = cc << 5;
    for (int i = 0; i < 2; ++i) {
      int idx = i * 256 + t;
      int row = idx >> 2, chv = idx & 3;
      g2l16(Et + (c0 + row) * 4096 + cin + chv * 8, &As[buf][idx * 8]);
      g2l16(P + (n0 + row) * 4096 + cin + chv * 8, &Bs[buf][idx * 8]);
    }
  };
  int l = t & 63, w = t >> 6;
  int wr = (w >> 1) << 6, wc = (w & 1) << 6;
  int lane16 = l & 15, kl = l >> 4;
  f32x4 acc[4][4];
  for (int m = 0; m < 4; ++m)
    for (int nn = 0; nn < 4; ++nn) acc[m][nn] = f32x4{0.f, 0.f, 0.f, 0.f};
  stage(0, 0);
  __syncthreads();
  for (int cc = 0; cc < 128; ++cc) {
    int buf = cc & 1;
    if (cc + 1 < 128) stage(buf ^ 1, cc + 1);
    bf16x8 af[4], bfr[4];
    for (int m = 0; m < 4; ++m)
      af[m] = *(const bf16x8*)&As[buf][(wr + m * 16 + lane16) * 32 + kl * 8];
    for (int nn = 0; nn < 4; ++nn)
      bfr[nn] = *(const bf16x8*)&Bs[buf][(wc + nn * 16 + lane16) * 32 + kl * 8];
    for (int m = 0; m < 4; ++m)
      for (int nn = 0; nn < 4; ++nn)
        acc[m][nn] = __builtin_amdgcn_mfma_f32_16x16x32_bf16(af[m], bfr[nn], acc[m][nn], 0, 0, 0);
    __syncthreads();
  }
  for (int m = 0; m < 4; ++m) {
    for (int r = 0; r < 4; ++r) {
      int crow = c0 + wr + m * 16 + kl * 4 + r;
      for (int nn = 0; nn < 4; ++nn) {
        int col = n0 + wc + nn * 16 + lane16;
        int bb = col >> 10, hw = col & 1023;
        Q[bb * 524288 + crow * 1024 + hw] = acc[m][nn][r];
      }
    }
  }
}

extern "C" void kernel_launch(void* const* d_in, const int* in_sizes, int n_in,
                              void* d_out, int out_size, void* d_ws, size_t ws_size,
                              hipStream_t stream) {
  const float* feat = (const float*)d_in[0];   // (16, 512, 32, 32)
  const float* cb = (const float*)d_in[1];     // (4096, 512)
  float* out = (float*)d_out;
  float* q_out = out;                          // 8388608
  float* a_out = out + 8388608;                // 67108864
  float* d_dist = out + 75497472;              // 67108864

  char* ws = (char*)d_ws;
  u16* Xh = (u16*)(ws + 0);                    // 16 MB  fp16 X (n,c)
  u16* Eh = (u16*)(ws + 16777216);             // 4 MB   fp16 E (k,c)
  u16* Et = (u16*)(ws + 20971520);             // 4 MB   bf16 E^T (c,k)
  float* xnorm = (float*)(ws + 25165824);      // 64 KB
  float* enorm = (float*)(ws + 25231360);      // 16 KB
  float* S1p = (float*)(ws + 25247744);        // 1 MB  [16][16384]
  float* STp = (float*)(ws + 26296320);        // 1 MB
  u16* P = (u16*)(ws + 27344896);              // 128 MB -> ends ~155 MB

  prep_x<<<256, 256, 0, stream>>>(feat, Xh, xnorm);
  prep_e<<<4096, 64, 0, stream>>>(cb, Eh, enorm);
  prep_et<<<512, 256, 0, stream>>>(cb, Et);
  gemm1_8ph<<<1024, 512, 0, stream>>>(Xh, Eh, xnorm, enorm, d_dist, S1p, STp);
  softmax_out<<<512, 256, 0, stream>>>(d_dist, xnorm, S1p, STp, a_out, P);
  gemm2<<<512, 256, 0, stream>>>(Et, P, q_out);
}